// Round 13
// baseline (2291.568 us; speedup 1.0000x reference)
//
#include <hip/hip_runtime.h>
#include <math.h>

#define BB 16
#define NN 2048
#define BN (BB * NN)
#define XS 512   // xcat row stride (x1|x2|x3|x4 concatenated)

typedef unsigned short u16;
typedef __attribute__((ext_vector_type(8))) short short8;
typedef __attribute__((ext_vector_type(4))) float f32x4;

__device__ __forceinline__ float leaky(float z) { return z > 0.f ? z : 0.2f * z; }
__device__ __forceinline__ float bnscale(float g) { return g / sqrtf(1.f + 1e-5f); }

// ---------------------------------------------------------------------------
// Wave-level top-K v4: SORTED LEADERBOARD (R9: 381->295 µs/stage).
// One-time bitonic sort of 64 per-lane-max keys; per round: pop lane 0 +
// O(1) sorted insert of popped lane's refill. Keys (ordered-uint(v)<<32)|~gid
// preserve exact (value desc, gid asc) order -> BIT-IDENTICAL output. Lazy
// top-3 + popmask rescan (rescan expected ~0.2x/call: Bin(19,1/64) >= 3).
// ---------------------------------------------------------------------------
__device__ __forceinline__ unsigned long long topk_key(float v, int gid) {
    unsigned b = __float_as_uint(v + 0.0f);                 // -0 -> +0
    unsigned u = b ^ ((unsigned)((int)b >> 31) | 0x80000000u);
    return ((unsigned long long)u << 32) | (unsigned)(~gid);
}

template<int K>
__device__ __forceinline__ void wave_topk(float lv[32], int lane, int* out) {
    static_assert(K <= 31, "pop budget exceeds per-lane candidates");
    unsigned pop = 0u;
    float v1 = -INFINITY, v2 = -INFINITY, v3 = -INFINITY;
    int m1 = 0, m2 = 0, m3 = 0;
    #pragma unroll
    for (int m = 0; m < 32; ++m) {
        float v = lv[m];
        bool c1 = v > v1, c2 = v > v2, c3 = v > v3;
        v3 = c2 ? v2 : (c3 ? v : v3);
        m3 = c2 ? m2 : (c3 ? m : m3);
        v2 = c1 ? v1 : (c2 ? v : v2);
        m2 = c1 ? m1 : (c2 ? m : m2);
        v1 = c1 ? v : v1;
        m1 = c1 ? m : m1;
    }
    int nvalid = 3;
    unsigned long long key = topk_key(v1, m1 * 64 + lane);
    #pragma unroll
    for (int kk = 2; kk <= 64; kk <<= 1) {
        #pragma unroll
        for (int j = kk >> 1; j > 0; j >>= 1) {
            unsigned long long ok = __shfl_xor(key, j);
            const bool keepMax = ((lane & kk) == 0) == ((lane & j) == 0);
            key = ((key > ok) == keepMax) ? key : ok;
        }
    }
    #pragma unroll 1
    for (int k = 0; k < K; ++k) {
        const unsigned long long w = __shfl(key, 0);
        const int wg = (int)(~(unsigned)w);
        if (lane == 0) out[k] = wg;
        if (k + 1 == K) break;
        const int s = wg & 63;               // wave-uniform source lane
        bool need = false;
        if (lane == s) {                     // pop my exposed candidate
            pop |= 1u << m1;
            v1 = v2; m1 = m2; v2 = v3; m2 = m3;
            need = (--nvalid == 0);
        }
        if (need) {                          // rare: rebuild top-3 (popmask)
            v1 = -INFINITY; v2 = -INFINITY; v3 = -INFINITY;
            m1 = 0; m2 = 0; m3 = 0;
            #pragma unroll
            for (int m = 0; m < 32; ++m) {
                float v = ((pop >> m) & 1u) ? -INFINITY : lv[m];
                bool c1 = v > v1, c2 = v > v2, c3 = v > v3;
                v3 = c2 ? v2 : (c3 ? v : v3);
                m3 = c2 ? m2 : (c3 ? m : m3);
                v2 = c1 ? v1 : (c2 ? v : v2);
                m2 = c1 ? m1 : (c2 ? m : m2);
                v1 = c1 ? v : v1;
                m1 = c1 ? m : m1;
            }
            nvalid = 3;
        }
        const unsigned long long e = __shfl(topk_key(v1, m1 * 64 + lane), s);
        const unsigned long long nb = __shfl_down(key, 1);
        const bool c1 = (lane < 63) && (nb > e);
        const bool c2 = (key > e);
        key = c1 ? nb : (c2 ? e : key);
    }
}

// ---------------------------------------------------------------------------
// Kernel 1: top-30 neighbors on raw xyz. x: [B,3,N]. 4 rows per block.
// ---------------------------------------------------------------------------
__global__ __launch_bounds__(256) void topk_xyz(const float* __restrict__ x,
                                                int* __restrict__ idx30) {
    const int tile = blockIdx.x;                 // b*512 + it
    const int b = tile >> 9;
    const int i0 = (tile & 511) * 4;
    __shared__ float dist[4][NN];
    const float* xb = x + (size_t)b * 3 * NN;
    float xi[4][3], ni[4];
    #pragma unroll
    for (int t = 0; t < 4; ++t) {
        xi[t][0] = xb[i0 + t];
        xi[t][1] = xb[NN + i0 + t];
        xi[t][2] = xb[2 * NN + i0 + t];
        ni[t] = xi[t][0] * xi[t][0] + xi[t][1] * xi[t][1] + xi[t][2] * xi[t][2];
    }
    for (int j = threadIdx.x; j < NN; j += 256) {
        float a0 = xb[j], a1 = xb[NN + j], a2 = xb[2 * NN + j];
        float nj = a0 * a0 + a1 * a1 + a2 * a2;
        #pragma unroll
        for (int t = 0; t < 4; ++t) {
            float dot = xi[t][0] * a0 + xi[t][1] * a1 + xi[t][2] * a2;
            dist[t][j] = 2.f * dot - ni[t] - nj;
        }
    }
    __syncthreads();
    const int w = threadIdx.x >> 6;
    const int lane = threadIdx.x & 63;
    float lv[32];
    #pragma unroll
    for (int m = 0; m < 32; ++m) lv[m] = dist[w][m * 64 + lane];
    wave_topk<30>(lv, lane, idx30 + ((size_t)b * NN + i0 + w) * 30);
}

// ---------------------------------------------------------------------------
// Kernel 2: hierarchical scale convs (k=5/20/30) + fused wf conv.
// Output row stride XS (writes the x1 slice of xcat).
// ---------------------------------------------------------------------------
__global__ __launch_bounds__(64) void hier_conv(
        const float* __restrict__ x, const int* __restrict__ idx30,
        const float* __restrict__ w1l, const float* __restrict__ g1l, const float* __restrict__ b1l,
        const float* __restrict__ w1b, const float* __restrict__ g1b, const float* __restrict__ b1b,
        const float* __restrict__ w1c, const float* __restrict__ g1c, const float* __restrict__ b1c,
        const float* __restrict__ wf,  const float* __restrict__ gf,  const float* __restrict__ bf_,
        float* __restrict__ x1out) {
    const int bi = blockIdx.x;            // b*N + i
    const int b = bi >> 11;
    const int i = bi & (NN - 1);
    const int o = threadIdx.x;            // 0..63
    __shared__ float xm[192];
    __shared__ float xjs[30][3];
    const float* xb = x + (size_t)b * 3 * NN;
    float xi0 = xb[i], xi1 = xb[NN + i], xi2 = xb[2 * NN + i];
    if (o < 30) {
        int j = idx30[(size_t)bi * 30 + o];
        xjs[o][0] = xb[j]; xjs[o][1] = xb[NN + j]; xjs[o][2] = xb[2 * NN + j];
    }
    float wl[6], wb[9], wc[7];
    #pragma unroll
    for (int c = 0; c < 6; ++c) wl[c] = w1l[o * 6 + c];
    #pragma unroll
    for (int c = 0; c < 9; ++c) wb[c] = w1b[o * 9 + c];
    #pragma unroll
    for (int c = 0; c < 7; ++c) wc[c] = w1c[o * 7 + c];
    float sl = bnscale(g1l[o]), bl = b1l[o];
    float sb = bnscale(g1b[o]), bbv = b1b[o];
    float sc = bnscale(g1c[o]), bc = b1c[o];
    __syncthreads();
    float aL = -INFINITY, aB = -INFINITY, aC = -INFINITY;
    for (int k = 0; k < 30; ++k) {
        float r0 = xjs[k][0] - xi0, r1 = xjs[k][1] - xi1, r2 = xjs[k][2] - xi2;
        float ss = r0 * r0 + r1 * r1 + r2 * r2;
        if (k < 5) {
            float y = wl[0]*r0 + wl[1]*r1 + wl[2]*r2 + wl[3]*xi0 + wl[4]*xi1 + wl[5]*xi2;
            aL = fmaxf(aL, leaky(y * sl + bl));
        }
        if (k < 20) {
            float nrm = sqrtf(ss) + 1e-8f;
            float y = wb[0]*r0 + wb[1]*r1 + wb[2]*r2
                    + wb[3]*(r0/nrm) + wb[4]*(r1/nrm) + wb[5]*(r2/nrm)
                    + wb[6]*xi0 + wb[7]*xi1 + wb[8]*xi2;
            aB = fmaxf(aB, leaky(y * sb + bbv));
        }
        {
            float d = sqrtf(ss);
            float y = wc[0]*r0 + wc[1]*r1 + wc[2]*r2 + wc[3]*xi0 + wc[4]*xi1 + wc[5]*xi2 + wc[6]*d;
            aC = fmaxf(aC, leaky(y * sc + bc));
        }
    }
    xm[o] = aL; xm[64 + o] = aB; xm[128 + o] = aC;
    __syncthreads();
    const float* wr = wf + (size_t)o * 192;
    float y = 0.f;
    #pragma unroll 8
    for (int c = 0; c < 192; c += 4) {
        float4 wv = *(const float4*)(wr + c);
        float4 xv = *(const float4*)(&xm[c]);
        y += wv.x * xv.x + wv.y * xv.y + wv.z * xv.z + wv.w * xv.w;
    }
    y = leaky(y * bnscale(gf[o]) + bf_[o]);
    x1out[(size_t)bi * XS + o] = y;
}

// ---------------------------------------------------------------------------
// Kernel 3: per-point squared norms over C (row stride XS)
// ---------------------------------------------------------------------------
template<int C>
__global__ __launch_bounds__(256) void rownorm(const float* __restrict__ xin,
                                               float* __restrict__ nrm) {
    int i = blockIdx.x * 256 + threadIdx.x;     // 0..B*N-1
    const float* r = xin + (size_t)i * XS;
    float s = 0.f;
    #pragma unroll 4
    for (int c = 0; c < C; c += 4) {
        float4 v = *(const float4*)(r + c);
        s += v.x * v.x + v.y * v.y + v.z * v.z + v.w * v.w;
    }
    nrm[i] = s;
}

// ---------------------------------------------------------------------------
// Kernel 3b: feature transpose — xT[b][c][i] = xin[(b*NN+i)*XS + c].
// Coalesced stores; reads are float4-per-row (L1-friendly). ~16 MB max.
// ---------------------------------------------------------------------------
template<int C>
__global__ __launch_bounds__(256) void transpose_feat(const float* __restrict__ xin,
                                                      float* __restrict__ xT) {
    const int blk = blockIdx.x;              // b*(NN/64) + tile
    const int b = blk >> 5;                  // NN/64 = 32 tiles
    const int i0 = (blk & 31) * 64;
    const int it = threadIdx.x & 63;
    const int cg = threadIdx.x >> 6;         // 4 c-groups
    const int i = i0 + it;
    const float* row = xin + (size_t)(b * NN + i) * XS;
    float* xTb = xT + (size_t)b * C * NN;
    #pragma unroll 1
    for (int c = cg * (C / 4); c < (cg + 1) * (C / 4); c += 4) {
        float4 v = *(const float4*)(row + c);
        xTb[(size_t)(c + 0) * NN + i] = v.x;
        xTb[(size_t)(c + 1) * NN + i] = v.y;
        xTb[(size_t)(c + 2) * NN + i] = v.z;
        xTb[(size_t)(c + 3) * NN + i] = v.w;
    }
}

// ---------------------------------------------------------------------------
// Kernel 4 (fused, FALLBACK for small ws): top-20 on C-dim features.
// Byte-exact R10 structure. Kept for the <151 MB workspace path only.
// ---------------------------------------------------------------------------
template<int C>
__global__ __launch_bounds__(256, 2) void topk_feat(const float* __restrict__ xin,
                                                    const float* __restrict__ nrm,
                                                    int* __restrict__ idx20) {
    const int i0 = blockIdx.x * 8;               // global point index
    const int b = i0 >> 11;
    const int li0 = i0 & (NN - 1);
    __shared__ float dist[8][NN];                // 64 KB
    const int tid = threadIdx.x;
    const float* xb = xin + (size_t)b * NN * XS;
    const float* xi_g = xb + (size_t)li0 * XS;
    float ni[8];
    #pragma unroll
    for (int t = 0; t < 8; ++t) ni[t] = nrm[b * NN + li0 + t];
    #pragma unroll 1
    for (int s = 0; s < 2; ++s) {
        const int j0 = tid + 1024 * s;           // rows j0 + 256*q, q=0..3
        float nj[4];
        #pragma unroll
        for (int q = 0; q < 4; ++q) nj[q] = nrm[b * NN + j0 + 256 * q];
        float acc[8][4];
        #pragma unroll
        for (int t = 0; t < 8; ++t)
            #pragma unroll
            for (int q = 0; q < 4; ++q) acc[t][q] = 0.f;
        #pragma unroll 1
        for (int c = 0; c < C; c += 16) {
            float4 v[4][4];
            #pragma unroll
            for (int q = 0; q < 4; ++q) {
                const float* xj = xb + (size_t)(j0 + 256 * q) * XS + c;
                v[q][0] = *(const float4*)(xj);
                v[q][1] = *(const float4*)(xj + 4);
                v[q][2] = *(const float4*)(xj + 8);
                v[q][3] = *(const float4*)(xj + 12);
            }
            #pragma unroll
            for (int t = 0; t < 8; ++t) {
                const float* xr = xi_g + (size_t)t * XS + c;   // wave-uniform
                float4 a0 = *(const float4*)(xr);
                float4 a1 = *(const float4*)(xr + 4);
                float4 a2 = *(const float4*)(xr + 8);
                float4 a3 = *(const float4*)(xr + 12);
                #pragma unroll
                for (int q = 0; q < 4; ++q) {
                    float sum = acc[t][q];
                    sum += a0.x * v[q][0].x; sum += a0.y * v[q][0].y;
                    sum += a0.z * v[q][0].z; sum += a0.w * v[q][0].w;
                    sum += a1.x * v[q][1].x; sum += a1.y * v[q][1].y;
                    sum += a1.z * v[q][1].z; sum += a1.w * v[q][1].w;
                    sum += a2.x * v[q][2].x; sum += a2.y * v[q][2].y;
                    sum += a2.z * v[q][2].z; sum += a2.w * v[q][2].w;
                    sum += a3.x * v[q][3].x; sum += a3.y * v[q][3].y;
                    sum += a3.z * v[q][3].z; sum += a3.w * v[q][3].w;
                    acc[t][q] = sum;
                }
            }
        }
        #pragma unroll
        for (int t = 0; t < 8; ++t)
            #pragma unroll
            for (int q = 0; q < 4; ++q)
                dist[t][j0 + 256 * q] = 2.f * acc[t][q] - ni[t] - nj[q];
    }
    __syncthreads();
    const int w = tid >> 6;
    const int lane = tid & 63;
    #pragma unroll 1
    for (int rr = 0; rr < 2; ++rr) {
        const int t = w + 4 * rr;
        float lv[32];
        #pragma unroll
        for (int m = 0; m < 32; ++m) lv[m] = dist[t][m * 64 + lane];
        wave_topk<20>(lv, lane, idx20 + (size_t)(i0 + t) * 20);
    }
}

// ---------------------------------------------------------------------------
// Kernel 4T v8: 8 rows, 512 thr, single-pass xT, XCD swizzle (R12) +
// TWO-PHASE dist (R5) for 4 blocks/CU. R12 post-mortem: swizzle made xT
// L2-served (FETCH 74->16.5 MB) but dur unchanged -> kernel is VALU-issue/
// latency bound at 2 blocks/CU (68 KB LDS), VALUBusy 84%. v8 halves the
// dist buffer (dist[4][NN]=32 KB, total 36 KB) -> 4 blocks/CU (512thr x 4 =
// 2048 = full CU). The xT re-read penalty that killed two-phase in R6 is
// gone (L2-served now); and R10's spill trap avoided: phases FULLY unrolled
// (static acc indices). Phase g: all threads write rows g*4..g*4+3 ->
// barrier -> waves w>>2==g extract row g*4+(w&3) (wave-uniform branch; each
// row by exactly one wave, same wave_topk) -> bit-identical indices.
// ---------------------------------------------------------------------------
template<int C>
__global__ __launch_bounds__(512, 4) void topk_feat_t(
        const float* __restrict__ xin, const float* __restrict__ xT,
        const float* __restrict__ nrm, int* __restrict__ idx20) {
    const int nwg = gridDim.x;                   // BN/8 = 4096 (div by 8)
    const int bid = blockIdx.x;
    const int swz = (bid & 7) * (nwg >> 3) + (bid >> 3);
    const int i0 = swz * 8;                      // global point index
    const int b = i0 >> 11;
    const int li0 = i0 & (NN - 1);
    __shared__ float dist[4][NN];                // 32 KB
    __shared__ float xi[8][C];                   // <= 4 KB
    const int tid = threadIdx.x;                 // 0..511
    for (int t4 = tid * 4; t4 < 8 * C; t4 += 2048) {
        const int t = t4 / C, c = t4 % C;
        *(float4*)&xi[t][c] = *(const float4*)&xin[(size_t)(i0 + t) * XS + c];
    }
    float ni[8];
    #pragma unroll
    for (int t = 0; t < 8; ++t) ni[t] = nrm[b * NN + li0 + t];
    const float4 nj = *(const float4*)&nrm[b * NN + tid * 4];
    const float* xTb = xT + (size_t)b * C * NN;
    __syncthreads();
    float acc[8][4];
    #pragma unroll
    for (int t = 0; t < 8; ++t)
        #pragma unroll
        for (int j = 0; j < 4; ++j) acc[t][j] = 0.f;
    #pragma unroll 1
    for (int c0 = 0; c0 < C; c0 += 4) {
        float4 vj[4];
        #pragma unroll
        for (int cc = 0; cc < 4; ++cc)
            vj[cc] = *(const float4*)&xTb[(size_t)(c0 + cc) * NN + tid * 4];
        #pragma unroll
        for (int t = 0; t < 8; ++t) {
            const float4 av = *(const float4*)&xi[t][c0];
            // c-ascending per output element (bit-exact vs fused kernel)
            acc[t][0] += av.x * vj[0].x;
            acc[t][1] += av.x * vj[0].y;
            acc[t][2] += av.x * vj[0].z;
            acc[t][3] += av.x * vj[0].w;
            acc[t][0] += av.y * vj[1].x;
            acc[t][1] += av.y * vj[1].y;
            acc[t][2] += av.y * vj[1].z;
            acc[t][3] += av.y * vj[1].w;
            acc[t][0] += av.z * vj[2].x;
            acc[t][1] += av.z * vj[2].y;
            acc[t][2] += av.z * vj[2].z;
            acc[t][3] += av.z * vj[2].w;
            acc[t][0] += av.w * vj[3].x;
            acc[t][1] += av.w * vj[3].y;
            acc[t][2] += av.w * vj[3].z;
            acc[t][3] += av.w * vj[3].w;
        }
    }
    const int w = tid >> 6;                      // wave id 0..7
    const int lane = tid & 63;
    #pragma unroll
    for (int g = 0; g < 2; ++g) {                // FULLY unrolled: static idx
        if (g) __syncthreads();                  // phase-0 lv reads done
        #pragma unroll
        for (int tt = 0; tt < 4; ++tt) {
            const int t = g * 4 + tt;            // compile-time constant
            float4 d;
            d.x = 2.f * acc[t][0] - ni[t] - nj.x;
            d.y = 2.f * acc[t][1] - ni[t] - nj.y;
            d.z = 2.f * acc[t][2] - ni[t] - nj.z;
            d.w = 2.f * acc[t][3] - ni[t] - nj.w;
            *(float4*)&dist[tt][tid * 4] = d;
        }
        __syncthreads();
        if ((w >> 2) == g) {                     // waves g*4..g*4+3 extract
            float lv[32];
            #pragma unroll
            for (int m = 0; m < 32; ++m) lv[m] = dist[w & 3][m * 64 + lane];
            wave_topk<20>(lv, lane, idx20 + (size_t)(i0 + g * 4 + (w & 3)) * 20);
        }
    }
}

// ---------------------------------------------------------------------------
// Kernel 5a: pconv — dense GEMM producing PT[BN][2*COUT]:
//   PT[i][o]      = sum_c w[o][c] * x[i][c]               (P)
//   PT[i][COUT+o] = sum_c (w[o][C+c]-w[o][c]) * x[i][c]   (T)
// R3: xt padded +4 floats/row (16-way LDS bank conflicts, 524K counted).
// ---------------------------------------------------------------------------
template<int C, int COUT>
__global__ __launch_bounds__(256) void pconv(
        const float* __restrict__ xin,   // rows stride XS
        const float* __restrict__ w,     // [COUT][2C]
        float* __restrict__ pt) {        // [BN][2*COUT] packed
    constexpr int O2 = 2 * COUT;
    constexpr int PB = 8192 / O2;
    constexpr int OG = O2 / 8;
    constexpr int PG = PB / 4;
    static_assert(OG * PG == 256, "tile mismatch");
    const int i0 = blockIdx.x * PB;
    __shared__ __align__(16) float xt[PB][C + 4];
    const int tid = threadIdx.x;
    for (int t = tid * 4; t < PB * C; t += 1024)
        *(float4*)(&xt[t / C][t % C]) =
            *(const float4*)(&xin[(size_t)(i0 + t / C) * XS + (t % C)]);
    __syncthreads();
    const int og = tid % OG, pg = tid / OG;
    const int o0 = og * 8, p0 = pg * 4;
    const bool thalf = (o0 >= COUT);
    const float* wb0 = w + (size_t)(thalf ? o0 - COUT : o0) * 2 * C;
    float acc[8][4];
    #pragma unroll
    for (int r = 0; r < 8; ++r)
        #pragma unroll
        for (int p = 0; p < 4; ++p) acc[r][p] = 0.f;
    #pragma unroll 2
    for (int c = 0; c < C; c += 4) {
        float4 wf[8];
        if (thalf) {
            #pragma unroll
            for (int r = 0; r < 8; ++r) {
                float4 a = *(const float4*)(wb0 + (size_t)r * 2 * C + c);
                float4 bq = *(const float4*)(wb0 + (size_t)r * 2 * C + C + c);
                wf[r].x = bq.x - a.x; wf[r].y = bq.y - a.y;
                wf[r].z = bq.z - a.z; wf[r].w = bq.w - a.w;
            }
        } else {
            #pragma unroll
            for (int r = 0; r < 8; ++r)
                wf[r] = *(const float4*)(wb0 + (size_t)r * 2 * C + c);
        }
        #pragma unroll
        for (int p = 0; p < 4; ++p) {
            float4 xv = *(const float4*)(&xt[p0 + p][c]);
            #pragma unroll
            for (int r = 0; r < 8; ++r)
                acc[r][p] += wf[r].x * xv.x + wf[r].y * xv.y
                           + wf[r].z * xv.z + wf[r].w * xv.w;
        }
    }
    #pragma unroll
    for (int p = 0; p < 4; ++p) {
        float* dst = pt + (size_t)(i0 + p0 + p) * O2 + o0;
        *(float4*)(dst)     = make_float4(acc[0][p], acc[1][p], acc[2][p], acc[3][p]);
        *(float4*)(dst + 4) = make_float4(acc[4][p], acc[5][p], acc[6][p], acc[7][p]);
    }
}

// ---------------------------------------------------------------------------
// Kernel 5b: gmax — gather 20 neighbor P-rows, max/min, select by sign(s),
// add T, bn+leaky, store into xcat (stride XS). idx20 is batch-local.
// ---------------------------------------------------------------------------
template<int COUT>
__global__ __launch_bounds__(256) void gmax(
        const float* __restrict__ pt, const int* __restrict__ idx20,
        const float* __restrict__ g, const float* __restrict__ bb,
        float* __restrict__ xout) {
    constexpr int TPP = COUT / 4;
    constexpr int PTS = 256 / TPP;
    const int i0 = blockIdx.x * PTS;
    const int base = i0 & ~(NN - 1);
    __shared__ int jl[PTS][20];
    const int tid = threadIdx.x;
    for (int t = tid; t < PTS * 20; t += 256)
        jl[t / 20][t % 20] = idx20[(size_t)(i0 + t / 20) * 20 + (t % 20)];
    __syncthreads();
    const int p = tid / TPP;
    const int q = (tid % TPP) * 4;
    const int i = i0 + p;
    float4 mx = make_float4(-INFINITY, -INFINITY, -INFINITY, -INFINITY);
    float4 mn = make_float4(INFINITY, INFINITY, INFINITY, INFINITY);
    #pragma unroll 4
    for (int k = 0; k < 20; ++k) {
        float4 v = *(const float4*)(pt + (size_t)(base + jl[p][k]) * (2 * COUT) + q);
        mx.x = fmaxf(mx.x, v.x); mx.y = fmaxf(mx.y, v.y);
        mx.z = fmaxf(mx.z, v.z); mx.w = fmaxf(mx.w, v.w);
        mn.x = fminf(mn.x, v.x); mn.y = fminf(mn.y, v.y);
        mn.z = fminf(mn.z, v.z); mn.w = fminf(mn.w, v.w);
    }
    float4 tv = *(const float4*)(pt + (size_t)i * (2 * COUT) + COUT + q);
    float4 gv = *(const float4*)(g + q);
    float4 bv = *(const float4*)(bb + q);
    float4 res;
    {
        float s = bnscale(gv.x); res.x = leaky(((s >= 0.f ? mx.x : mn.x) + tv.x) * s + bv.x);
    }{
        float s = bnscale(gv.y); res.y = leaky(((s >= 0.f ? mx.y : mn.y) + tv.y) * s + bv.y);
    }{
        float s = bnscale(gv.z); res.z = leaky(((s >= 0.f ? mx.z : mn.z) + tv.z) * s + bv.z);
    }{
        float s = bnscale(gv.w); res.w = leaky(((s >= 0.f ? mx.w : mn.w) + tv.w) * s + bv.w);
    }
    *(float4*)(xout + (size_t)i * XS + q) = res;
}

// ---------------------------------------------------------------------------
// Kernel S: split fp32 -> bf16 hi/lo pair (round-to-nearest-even).
// v = hi + lo + O(2^-18 |v|).
// ---------------------------------------------------------------------------
__global__ __launch_bounds__(256) void split_bf16(const float* __restrict__ in,
                                                  u16* __restrict__ hi,
                                                  u16* __restrict__ lo, int n4) {
    int i = blockIdx.x * 256 + threadIdx.x;
    if (i >= n4) return;
    float4 v = ((const float4*)in)[i];
    float vv[4] = {v.x, v.y, v.z, v.w};
    unsigned h[4], l[4];
    #pragma unroll
    for (int t = 0; t < 4; ++t) {
        unsigned u = __float_as_uint(vv[t]);
        unsigned r = (u + 0x7FFFu + ((u >> 16) & 1u)) >> 16;
        h[t] = r;
        float res = vv[t] - __uint_as_float(r << 16);
        unsigned u2 = __float_as_uint(res);
        l[t] = (u2 + 0x7FFFu + ((u2 >> 16) & 1u)) >> 16;
    }
    ((uint2*)hi)[i] = make_uint2(h[0] | (h[1] << 16), h[2] | (h[3] << 16));
    ((uint2*)lo)[i] = make_uint2(l[0] | (l[1] << 16), l[2] | (l[3] << 16));
}

// ---------------------------------------------------------------------------
// Kernel 6 (MFMA, v2): w5 conv via bf16x3 split-float MFMA, register-tiled.
// Each wave owns a 64x64 tile (4 m-frags x 4 n-frags, 64 acc VGPRs);
// block = 4 waves = 64 m x 256 oc. R2: dropped 576 -> <100 µs vs v1.
// ---------------------------------------------------------------------------
__global__ __launch_bounds__(256) void conv5_mfma2(
        const u16* __restrict__ xhi, const u16* __restrict__ xlo,
        const u16* __restrict__ whi, const u16* __restrict__ wlo,
        const float* __restrict__ g5, const float* __restrict__ b5,
        float* __restrict__ pmax, float* __restrict__ psum) {
    const int mblk = blockIdx.x >> 2;            // BN/64 m-blocks
    const int nblk = blockIdx.x & 3;             // 4 n-groups x 256 oc
    const int wv = threadIdx.x >> 6;
    const int lane = threadIdx.x & 63;
    const int row = lane & 15;
    const int quad = lane >> 4;
    const int m0 = mblk * 64;
    const int n0 = nblk * 256 + wv * 64;
    const u16* xh = xhi + (size_t)(m0 + row) * 512 + quad * 8;
    const u16* xl = xlo + (size_t)(m0 + row) * 512 + quad * 8;
    const u16* wh = whi + (size_t)(n0 + row) * 512 + quad * 8;
    const u16* wl = wlo + (size_t)(n0 + row) * 512 + quad * 8;
    f32x4 acc[4][4];
    #pragma unroll
    for (int f = 0; f < 4; ++f)
        #pragma unroll
        for (int g = 0; g < 4; ++g) acc[f][g] = (f32x4){0.f, 0.f, 0.f, 0.f};
    #pragma unroll 1
    for (int k = 0; k < 512; k += 32) {
        short8 ah[4], al[4], bh[4], bl[4];
        #pragma unroll
        for (int f = 0; f < 4; ++f) {
            ah[f] = *(const short8*)(xh + (size_t)f * 16 * 512 + k);
            al[f] = *(const short8*)(xl + (size_t)f * 16 * 512 + k);
        }
        #pragma unroll
        for (int g = 0; g < 4; ++g) {
            bh[g] = *(const short8*)(wh + (size_t)g * 16 * 512 + k);
            bl[g] = *(const short8*)(wl + (size_t)g * 16 * 512 + k);
        }
        #pragma unroll
        for (int f = 0; f < 4; ++f)
            #pragma unroll
            for (int g = 0; g < 4; ++g) {
                acc[f][g] = __builtin_amdgcn_mfma_f32_16x16x32_bf16(ah[f], bh[g], acc[f][g], 0, 0, 0);
                acc[f][g] = __builtin_amdgcn_mfma_f32_16x16x32_bf16(ah[f], bl[g], acc[f][g], 0, 0, 0);
                acc[f][g] = __builtin_amdgcn_mfma_f32_16x16x32_bf16(al[f], bh[g], acc[f][g], 0, 0, 0);
            }
    }
    const int b = m0 >> 11;
    const int ch0 = (m0 & (NN - 1)) >> 4;        // chunk of 16 pts
    #pragma unroll
    for (int f = 0; f < 4; ++f) {
        const int ch = ch0 + f;
        #pragma unroll
        for (int g = 0; g < 4; ++g) {
            const int oc = n0 + g * 16 + row;
            float s = bnscale(g5[oc]), bv = b5[oc];
            float mx = -INFINITY, sm = 0.f;
            #pragma unroll
            for (int r = 0; r < 4; ++r) {
                float z = leaky(acc[f][g][r] * s + bv);
                mx = fmaxf(mx, z); sm += z;
            }
            mx = fmaxf(mx, __shfl_xor(mx, 16)); sm += __shfl_xor(sm, 16);
            mx = fmaxf(mx, __shfl_xor(mx, 32)); sm += __shfl_xor(sm, 32);
            if (lane < 16) {
                pmax[((size_t)b * 128 + ch) * 1024 + oc] = mx;
                psum[((size_t)b * 128 + ch) * 1024 + oc] = sm;
            }
        }
    }
}

// ---------------------------------------------------------------------------
// Kernel 6 (fallback): fp32 conv5+pool, 32 pts/block, 64 chunks.
// ---------------------------------------------------------------------------
__global__ __launch_bounds__(256, 3) void conv5_pool(
        const float* __restrict__ xcat,
        const float* __restrict__ w5, const float* __restrict__ g5,
        const float* __restrict__ b5,
        float* __restrict__ pmax, float* __restrict__ psum) {
    const int blk = blockIdx.x;                  // b*64 + chunk
    const int b = blk >> 6;
    const int ch = blk & 63;
    const int i0 = ch * 32;
    const float* xrow = xcat + ((size_t)b * NN + i0) * XS;
    const int tid = threadIdx.x;
    float acc[4][32];
    #pragma unroll
    for (int q = 0; q < 4; ++q)
        #pragma unroll
        for (int p = 0; p < 32; ++p) acc[q][p] = 0.f;
    #pragma unroll 1
    for (int c = 0; c < 512; c += 4) {
        float4 wv[4];
        #pragma unroll
        for (int q = 0; q < 4; ++q)
            wv[q] = *(const float4*)(w5 + (size_t)(tid + 256 * q) * 512 + c);
        #pragma unroll
        for (int p = 0; p < 32; ++p) {
            float4 xs = *(const float4*)(xrow + (size_t)p * XS + c);
            #pragma unroll
            for (int q = 0; q < 4; ++q)
                acc[q][p] += wv[q].x * xs.x + wv[q].y * xs.y
                           + wv[q].z * xs.z + wv[q].w * xs.w;
        }
    }
    #pragma unroll
    for (int q = 0; q < 4; ++q) {
        int oc = tid + 256 * q;
        float s = bnscale(g5[oc]), bv = b5[oc];
        float m = -INFINITY, sm = 0.f;
        #pragma unroll
        for (int p = 0; p < 32; ++p) {
            float z = leaky(acc[q][p] * s + bv);
            m = fmaxf(m, z);
            sm += z;
        }
        pmax[((size_t)b * 64 + ch) * 1024 + oc] = m;
        psum[((size_t)b * 64 + ch) * 1024 + oc] = sm;
    }
}

// ---------------------------------------------------------------------------
// Kernel 6b: pool_reduce — reduce pmax/psum over nch chunks into h[b][2048]
// with real parallelism (BB*8 = 128 blocks, coalesced 1024-wide reads).
// ---------------------------------------------------------------------------
__global__ __launch_bounds__(256) void pool_reduce(
        const float* __restrict__ pmax, const float* __restrict__ psum,
        int nch, float* __restrict__ hbuf) {
    const int b = blockIdx.x >> 3;
    const int g = blockIdx.x & 7;                // 8 oc-groups of 128
    const int tid = threadIdx.x;
    const int oc = g * 128 + (tid & 127);
    const int half = tid >> 7;                   // 2 chunk-halves
    const int h0 = half * (nch / 2);
    float m = -INFINITY, sm = 0.f;
    for (int ch = h0; ch < h0 + nch / 2; ++ch) {
        m = fmaxf(m, pmax[((size_t)b * nch + ch) * 1024 + oc]);
        sm += psum[((size_t)b * nch + ch) * 1024 + oc];
    }
    __shared__ float sx[128], ss[128];
    if (half == 1) { sx[tid & 127] = m; ss[tid & 127] = sm; }
    __syncthreads();
    if (half == 0) {
        m = fmaxf(m, sx[tid & 127]);
        sm += ss[tid & 127];
        hbuf[(size_t)b * 2048 + oc] = m;
        hbuf[(size_t)b * 2048 + 1024 + oc] = sm * (1.0f / 2048.0f);
    }
}

// ---------------------------------------------------------------------------
// Kernel 7: 3 FC layers on precomputed h. One block per batch row.
// ---------------------------------------------------------------------------
__global__ __launch_bounds__(256) void fc_head(
        const float* __restrict__ hbuf,
        const float* __restrict__ wl1, const float* __restrict__ g6, const float* __restrict__ b6,
        const float* __restrict__ wl2, const float* __restrict__ bl2,
        const float* __restrict__ g7, const float* __restrict__ b7,
        const float* __restrict__ wl3, const float* __restrict__ bl3,
        float* __restrict__ out) {
    const int b = blockIdx.x;
    const int tid = threadIdx.x;
    __shared__ float h[2048];
    __shared__ float h1[512];
    __shared__ float h2[256];
    for (int t = tid * 4; t < 2048; t += 1024)
        *(float4*)(&h[t]) = *(const float4*)(hbuf + (size_t)b * 2048 + t);
    __syncthreads();
    #pragma unroll
    for (int q = 0; q < 2; ++q) {
        int o = tid + 256 * q;
        const float* wr = wl1 + (size_t)o * 2048;
        float y = 0.f;
        for (int c = 0; c < 2048; c += 4) {
            float4 wv = *(const float4*)(wr + c);
            float4 hv = *(const float4*)(&h[c]);
            y += wv.x * hv.x + wv.y * hv.y + wv.z * hv.z + wv.w * hv.w;
        }
        y = y * bnscale(g6[o]) + b6[o];
        h1[o] = leaky(y);
    }
    __syncthreads();
    {
        int o = tid;
        const float* wr = wl2 + (size_t)o * 512;
        float y = 0.f;
        for (int c = 0; c < 512; c += 4) {
            float4 wv = *(const float4*)(wr + c);
            float4 hv = *(const float4*)(&h1[c]);
            y += wv.x * hv.x + wv.y * hv.y + wv.z * hv.z + wv.w * hv.w;
        }
        y = (y + bl2[o]) * bnscale(g7[o]) + b7[o];
        h2[o] = leaky(y);
    }
    __syncthreads();
    if (tid < 7) {
        const float* wr = wl3 + tid * 256;
        float y = 0.f;
        for (int c = 0; c < 256; ++c) y += wr[c] * h2[c];
        out[b * 7 + tid] = y + bl3[tid];
    }
}

// ---------------------------------------------------------------------------
extern "C" void kernel_launch(void* const* d_in, const int* in_sizes, int n_in,
                              void* d_out, int out_size, void* d_ws, size_t ws_size,
                              hipStream_t stream) {
    const float* x   = (const float*)d_in[0];
    const float* w1l = (const float*)d_in[1];
    const float* g1l = (const float*)d_in[2];
    const float* b1l = (const float*)d_in[3];
    const float* w1b = (const float*)d_in[4];
    const float* g1b = (const float*)d_in[5];
    const float* b1b = (const float*)d_in[6];
    const float* w1c = (const float*)d_in[7];
    const float* g1c = (const float*)d_in[8];
    const float* b1c = (const float*)d_in[9];
    const float* wf  = (const float*)d_in[10];
    const float* gf  = (const float*)d_in[11];
    const float* bf_ = (const float*)d_in[12];
    const float* w2  = (const float*)d_in[13];
    const float* g2  = (const float*)d_in[14];
    const float* b2  = (const float*)d_in[15];
    const float* w3  = (const float*)d_in[16];
    const float* g3  = (const float*)d_in[17];
    const float* b3  = (const float*)d_in[18];
    const float* w4  = (const float*)d_in[19];
    const float* g4  = (const float*)d_in[20];
    const float* b4  = (const float*)d_in[21];
    const float* w5  = (const float*)d_in[22];
    const float* g5  = (const float*)d_in[23];
    const float* b5  = (const float*)d_in[24];
    const float* wl1 = (const float*)d_in[25];
    const float* g6  = (const float*)d_in[26];
    const float* b6  = (const float*)d_in[27];
    const float* wl2 = (const float*)d_in[28];
    const float* bl2 = (const float*)d_in[29];
    const float* g7  = (const float*)d_in[30];
    const float* b7  = (const float*)d_in[31];
    const float* wl3 = (const float*)d_in[32];
    const float* bl3 = (const float*)d_in[33];
    float* out = (float*)d_out;

    // Workspace layout (MB offsets):
    //  idxb [0,4)  xcat [4,68)  nrm [68,68.125)  hbuf [68.25,68.5)  pt [69,101)
    //  xT [69,85): transposed features, live ONLY between transpose_feat and
    //    topk_feat_t of each stage — pt/xlo (dead then) overlay it afterward.
    //  MFMA path (needs 151 MB): xlo overlays pt [69,101), xhi [101,133),
    //  whi [133,134), wlo [134,135), pmax [135,143), psum [143,151)
    //  Fallback (<151 MB): pmax [69,73), psum [73,77) (64-chunk), fused topk.
    char* ws = (char*)d_ws;
    int*   idxb = (int*)(ws);
    float* xcat = (float*)(ws + ((size_t)4  << 20));
    float* nrm  = (float*)(ws + ((size_t)68 << 20));
    float* hbuf = (float*)(ws + ((size_t)68 << 20) + ((size_t)256 << 10));
    float* pt   = (float*)(ws + ((size_t)69 << 20));
    float* xT   = (float*)(ws + ((size_t)69 << 20));
    const bool mfma_ok = ws_size >= ((size_t)151 << 20);
    u16* xlo = (u16*)(ws + ((size_t)69  << 20));
    u16* xhi = (u16*)(ws + ((size_t)101 << 20));
    u16* whi = (u16*)(ws + ((size_t)133 << 20));
    u16* wlo = (u16*)(ws + ((size_t)134 << 20));
    float* pmax = mfma_ok ? (float*)(ws + ((size_t)135 << 20))
                          : (float*)(ws + ((size_t)69 << 20));
    float* psum = mfma_ok ? (float*)(ws + ((size_t)143 << 20))
                          : (float*)(ws + ((size_t)73 << 20));
    const int nch = mfma_ok ? 128 : 64;
    float* x1 = xcat;
    float* x2 = xcat + 64;
    float* x3 = xcat + 128;
    float* x4 = xcat + 256;

    // 1. top-30 on xyz
    topk_xyz<<<BB * NN / 4, 256, 0, stream>>>(x, idxb);
    // 2. hierarchical scale convs + wf conv -> x1 slice of xcat
    hier_conv<<<BB * NN, 64, 0, stream>>>(x, idxb, w1l, g1l, b1l, w1b, g1b, b1b,
                                          w1c, g1c, b1c, wf, gf, bf_, x1);
    // 3. edge stage 2: x1(64) -> x2(64)
    rownorm<64><<<BN / 256, 256, 0, stream>>>(x1, nrm);
    if (mfma_ok) {
        transpose_feat<64><<<BB * 32, 256, 0, stream>>>(x1, xT);
        topk_feat_t<64><<<BN / 8, 512, 0, stream>>>(x1, xT, nrm, idxb);
    } else {
        topk_feat<64><<<BN / 8, 256, 0, stream>>>(x1, nrm, idxb);
    }
    pconv<64, 64><<<BN / 64, 256, 0, stream>>>(x1, w2, pt);
    gmax<64><<<BN / 16, 256, 0, stream>>>(pt, idxb, g2, b2, x2);
    // 4. edge stage 3: x2(64) -> x3(128)
    rownorm<64><<<BN / 256, 256, 0, stream>>>(x2, nrm);
    if (mfma_ok) {
        transpose_feat<64><<<BB * 32, 256, 0, stream>>>(x2, xT);
        topk_feat_t<64><<<BN / 8, 512, 0, stream>>>(x2, xT, nrm, idxb);
    } else {
        topk_feat<64><<<BN / 8, 256, 0, stream>>>(x2, nrm, idxb);
    }
    pconv<64, 128><<<BN / 32, 256, 0, stream>>>(x2, w3, pt);
    gmax<128><<<BN / 8, 256, 0, stream>>>(pt, idxb, g3, b3, x3);
    // 5. edge stage 4: x3(128) -> x4(256), two column halves
    rownorm<128><<<BN / 256, 256, 0, stream>>>(x3, nrm);
    if (mfma_ok) {
        transpose_feat<128><<<BB * 32, 256, 0, stream>>>(x3, xT);
        topk_feat_t<128><<<BN / 8, 512, 0, stream>>>(x3, xT, nrm, idxb);
    } else {
        topk_feat<128><<<BN / 8, 256, 0, stream>>>(x3, nrm, idxb);
    }
    for (int h = 0; h < 2; ++h) {
        pconv<128, 128><<<BN / 32, 256, 0, stream>>>(x3, w4 + (size_t)h * 128 * 256, pt);
        gmax<128><<<BN / 8, 256, 0, stream>>>(pt, idxb, g4 + h * 128, b4 + h * 128,
                                              x4 + h * 128);
    }
    // 6. w5 conv + pooling partials
    if (mfma_ok) {
        split_bf16<<<(BN * 512 / 4) / 256, 256, 0, stream>>>(xcat, xhi, xlo, BN * 512 / 4);
        split_bf16<<<(1024 * 512 / 4) / 256, 256, 0, stream>>>(w5, whi, wlo, 1024 * 512 / 4);
        conv5_mfma2<<<(BN / 64) * 4, 256, 0, stream>>>(xhi, xlo, whi, wlo,
                                                       g5, b5, pmax, psum);
    } else {
        conv5_pool<<<BB * 64, 256, 0, stream>>>(xcat, w5, g5, b5, pmax, psum);
    }
    // 7. parallel pool reduce + FC head
    pool_reduce<<<BB * 8, 256, 0, stream>>>(pmax, psum, nch, hbuf);
    fc_head<<<BB, 256, 0, stream>>>(hbuf, wl1, g6, b6, wl2, bl2,
                                    g7, b7, wl3, bl3, out);
}

// Round 14
// 2189.461 us; speedup vs baseline: 1.0466x; 1.0466x over previous
//
#include <hip/hip_runtime.h>
#include <math.h>

#define BB 16
#define NN 2048
#define BN (BB * NN)
#define XS 512   // xcat row stride (x1|x2|x3|x4 concatenated)

typedef unsigned short u16;
typedef __attribute__((ext_vector_type(8))) short short8;
typedef __attribute__((ext_vector_type(4))) float f32x4;

__device__ __forceinline__ float leaky(float z) { return z > 0.f ? z : 0.2f * z; }
__device__ __forceinline__ float bnscale(float g) { return g / sqrtf(1.f + 1e-5f); }

// ---------------------------------------------------------------------------
// Wave-level top-K v4: SORTED LEADERBOARD (R9: 381->295 µs/stage).
// One-time bitonic sort of 64 per-lane-max keys; per round: pop lane 0 +
// O(1) sorted insert of popped lane's refill. Keys (ordered-uint(v)<<32)|~gid
// preserve exact (value desc, gid asc) order -> BIT-IDENTICAL output. Lazy
// top-3 + popmask rescan (rescan expected ~0.2x/call: Bin(19,1/64) >= 3).
// ---------------------------------------------------------------------------
__device__ __forceinline__ unsigned long long topk_key(float v, int gid) {
    unsigned b = __float_as_uint(v + 0.0f);                 // -0 -> +0
    unsigned u = b ^ ((unsigned)((int)b >> 31) | 0x80000000u);
    return ((unsigned long long)u << 32) | (unsigned)(~gid);
}

template<int K>
__device__ __forceinline__ void wave_topk(float lv[32], int lane, int* out) {
    static_assert(K <= 31, "pop budget exceeds per-lane candidates");
    unsigned pop = 0u;
    float v1 = -INFINITY, v2 = -INFINITY, v3 = -INFINITY;
    int m1 = 0, m2 = 0, m3 = 0;
    #pragma unroll
    for (int m = 0; m < 32; ++m) {
        float v = lv[m];
        bool c1 = v > v1, c2 = v > v2, c3 = v > v3;
        v3 = c2 ? v2 : (c3 ? v : v3);
        m3 = c2 ? m2 : (c3 ? m : m3);
        v2 = c1 ? v1 : (c2 ? v : v2);
        m2 = c1 ? m1 : (c2 ? m : m2);
        v1 = c1 ? v : v1;
        m1 = c1 ? m : m1;
    }
    int nvalid = 3;
    unsigned long long key = topk_key(v1, m1 * 64 + lane);
    #pragma unroll
    for (int kk = 2; kk <= 64; kk <<= 1) {
        #pragma unroll
        for (int j = kk >> 1; j > 0; j >>= 1) {
            unsigned long long ok = __shfl_xor(key, j);
            const bool keepMax = ((lane & kk) == 0) == ((lane & j) == 0);
            key = ((key > ok) == keepMax) ? key : ok;
        }
    }
    #pragma unroll 1
    for (int k = 0; k < K; ++k) {
        const unsigned long long w = __shfl(key, 0);
        const int wg = (int)(~(unsigned)w);
        if (lane == 0) out[k] = wg;
        if (k + 1 == K) break;
        const int s = wg & 63;               // wave-uniform source lane
        bool need = false;
        if (lane == s) {                     // pop my exposed candidate
            pop |= 1u << m1;
            v1 = v2; m1 = m2; v2 = v3; m2 = m3;
            need = (--nvalid == 0);
        }
        if (need) {                          // rare: rebuild top-3 (popmask)
            v1 = -INFINITY; v2 = -INFINITY; v3 = -INFINITY;
            m1 = 0; m2 = 0; m3 = 0;
            #pragma unroll
            for (int m = 0; m < 32; ++m) {
                float v = ((pop >> m) & 1u) ? -INFINITY : lv[m];
                bool c1 = v > v1, c2 = v > v2, c3 = v > v3;
                v3 = c2 ? v2 : (c3 ? v : v3);
                m3 = c2 ? m2 : (c3 ? m : m3);
                v2 = c1 ? v1 : (c2 ? v : v2);
                m2 = c1 ? m1 : (c2 ? m : m2);
                v1 = c1 ? v : v1;
                m1 = c1 ? m : m1;
            }
            nvalid = 3;
        }
        const unsigned long long e = __shfl(topk_key(v1, m1 * 64 + lane), s);
        const unsigned long long nb = __shfl_down(key, 1);
        const bool c1 = (lane < 63) && (nb > e);
        const bool c2 = (key > e);
        key = c1 ? nb : (c2 ? e : key);
    }
}

// ---------------------------------------------------------------------------
// Kernel 1: top-30 neighbors on raw xyz. x: [B,3,N]. 4 rows per block.
// ---------------------------------------------------------------------------
__global__ __launch_bounds__(256) void topk_xyz(const float* __restrict__ x,
                                                int* __restrict__ idx30) {
    const int tile = blockIdx.x;                 // b*512 + it
    const int b = tile >> 9;
    const int i0 = (tile & 511) * 4;
    __shared__ float dist[4][NN];
    const float* xb = x + (size_t)b * 3 * NN;
    float xi[4][3], ni[4];
    #pragma unroll
    for (int t = 0; t < 4; ++t) {
        xi[t][0] = xb[i0 + t];
        xi[t][1] = xb[NN + i0 + t];
        xi[t][2] = xb[2 * NN + i0 + t];
        ni[t] = xi[t][0] * xi[t][0] + xi[t][1] * xi[t][1] + xi[t][2] * xi[t][2];
    }
    for (int j = threadIdx.x; j < NN; j += 256) {
        float a0 = xb[j], a1 = xb[NN + j], a2 = xb[2 * NN + j];
        float nj = a0 * a0 + a1 * a1 + a2 * a2;
        #pragma unroll
        for (int t = 0; t < 4; ++t) {
            float dot = xi[t][0] * a0 + xi[t][1] * a1 + xi[t][2] * a2;
            dist[t][j] = 2.f * dot - ni[t] - nj;
        }
    }
    __syncthreads();
    const int w = threadIdx.x >> 6;
    const int lane = threadIdx.x & 63;
    float lv[32];
    #pragma unroll
    for (int m = 0; m < 32; ++m) lv[m] = dist[w][m * 64 + lane];
    wave_topk<30>(lv, lane, idx30 + ((size_t)b * NN + i0 + w) * 30);
}

// ---------------------------------------------------------------------------
// Kernel 2: hierarchical scale convs (k=5/20/30) + fused wf conv.
// Output row stride XS (writes the x1 slice of xcat).
// ---------------------------------------------------------------------------
__global__ __launch_bounds__(64) void hier_conv(
        const float* __restrict__ x, const int* __restrict__ idx30,
        const float* __restrict__ w1l, const float* __restrict__ g1l, const float* __restrict__ b1l,
        const float* __restrict__ w1b, const float* __restrict__ g1b, const float* __restrict__ b1b,
        const float* __restrict__ w1c, const float* __restrict__ g1c, const float* __restrict__ b1c,
        const float* __restrict__ wf,  const float* __restrict__ gf,  const float* __restrict__ bf_,
        float* __restrict__ x1out) {
    const int bi = blockIdx.x;            // b*N + i
    const int b = bi >> 11;
    const int i = bi & (NN - 1);
    const int o = threadIdx.x;            // 0..63
    __shared__ float xm[192];
    __shared__ float xjs[30][3];
    const float* xb = x + (size_t)b * 3 * NN;
    float xi0 = xb[i], xi1 = xb[NN + i], xi2 = xb[2 * NN + i];
    if (o < 30) {
        int j = idx30[(size_t)bi * 30 + o];
        xjs[o][0] = xb[j]; xjs[o][1] = xb[NN + j]; xjs[o][2] = xb[2 * NN + j];
    }
    float wl[6], wb[9], wc[7];
    #pragma unroll
    for (int c = 0; c < 6; ++c) wl[c] = w1l[o * 6 + c];
    #pragma unroll
    for (int c = 0; c < 9; ++c) wb[c] = w1b[o * 9 + c];
    #pragma unroll
    for (int c = 0; c < 7; ++c) wc[c] = w1c[o * 7 + c];
    float sl = bnscale(g1l[o]), bl = b1l[o];
    float sb = bnscale(g1b[o]), bbv = b1b[o];
    float sc = bnscale(g1c[o]), bc = b1c[o];
    __syncthreads();
    float aL = -INFINITY, aB = -INFINITY, aC = -INFINITY;
    for (int k = 0; k < 30; ++k) {
        float r0 = xjs[k][0] - xi0, r1 = xjs[k][1] - xi1, r2 = xjs[k][2] - xi2;
        float ss = r0 * r0 + r1 * r1 + r2 * r2;
        if (k < 5) {
            float y = wl[0]*r0 + wl[1]*r1 + wl[2]*r2 + wl[3]*xi0 + wl[4]*xi1 + wl[5]*xi2;
            aL = fmaxf(aL, leaky(y * sl + bl));
        }
        if (k < 20) {
            float nrm = sqrtf(ss) + 1e-8f;
            float y = wb[0]*r0 + wb[1]*r1 + wb[2]*r2
                    + wb[3]*(r0/nrm) + wb[4]*(r1/nrm) + wb[5]*(r2/nrm)
                    + wb[6]*xi0 + wb[7]*xi1 + wb[8]*xi2;
            aB = fmaxf(aB, leaky(y * sb + bbv));
        }
        {
            float d = sqrtf(ss);
            float y = wc[0]*r0 + wc[1]*r1 + wc[2]*r2 + wc[3]*xi0 + wc[4]*xi1 + wc[5]*xi2 + wc[6]*d;
            aC = fmaxf(aC, leaky(y * sc + bc));
        }
    }
    xm[o] = aL; xm[64 + o] = aB; xm[128 + o] = aC;
    __syncthreads();
    const float* wr = wf + (size_t)o * 192;
    float y = 0.f;
    #pragma unroll 8
    for (int c = 0; c < 192; c += 4) {
        float4 wv = *(const float4*)(wr + c);
        float4 xv = *(const float4*)(&xm[c]);
        y += wv.x * xv.x + wv.y * xv.y + wv.z * xv.z + wv.w * xv.w;
    }
    y = leaky(y * bnscale(gf[o]) + bf_[o]);
    x1out[(size_t)bi * XS + o] = y;
}

// ---------------------------------------------------------------------------
// Kernel 3: per-point squared norms over C (row stride XS)
// ---------------------------------------------------------------------------
template<int C>
__global__ __launch_bounds__(256) void rownorm(const float* __restrict__ xin,
                                               float* __restrict__ nrm) {
    int i = blockIdx.x * 256 + threadIdx.x;     // 0..B*N-1
    const float* r = xin + (size_t)i * XS;
    float s = 0.f;
    #pragma unroll 4
    for (int c = 0; c < C; c += 4) {
        float4 v = *(const float4*)(r + c);
        s += v.x * v.x + v.y * v.y + v.z * v.z + v.w * v.w;
    }
    nrm[i] = s;
}

// ---------------------------------------------------------------------------
// Kernel 3b: feature transpose — xT[b][c][i] = xin[(b*NN+i)*XS + c].
// Coalesced stores; reads are float4-per-row (L1-friendly). ~16 MB max.
// ---------------------------------------------------------------------------
template<int C>
__global__ __launch_bounds__(256) void transpose_feat(const float* __restrict__ xin,
                                                      float* __restrict__ xT) {
    const int blk = blockIdx.x;              // b*(NN/64) + tile
    const int b = blk >> 5;                  // NN/64 = 32 tiles
    const int i0 = (blk & 31) * 64;
    const int it = threadIdx.x & 63;
    const int cg = threadIdx.x >> 6;         // 4 c-groups
    const int i = i0 + it;
    const float* row = xin + (size_t)(b * NN + i) * XS;
    float* xTb = xT + (size_t)b * C * NN;
    #pragma unroll 1
    for (int c = cg * (C / 4); c < (cg + 1) * (C / 4); c += 4) {
        float4 v = *(const float4*)(row + c);
        xTb[(size_t)(c + 0) * NN + i] = v.x;
        xTb[(size_t)(c + 1) * NN + i] = v.y;
        xTb[(size_t)(c + 2) * NN + i] = v.z;
        xTb[(size_t)(c + 3) * NN + i] = v.w;
    }
}

// ---------------------------------------------------------------------------
// Kernel 4 (fused, FALLBACK for small ws): top-20 on C-dim features.
// Byte-exact R10 structure. Kept for the <151 MB workspace path only.
// ---------------------------------------------------------------------------
template<int C>
__global__ __launch_bounds__(256, 2) void topk_feat(const float* __restrict__ xin,
                                                    const float* __restrict__ nrm,
                                                    int* __restrict__ idx20) {
    const int i0 = blockIdx.x * 8;               // global point index
    const int b = i0 >> 11;
    const int li0 = i0 & (NN - 1);
    __shared__ float dist[8][NN];                // 64 KB
    const int tid = threadIdx.x;
    const float* xb = xin + (size_t)b * NN * XS;
    const float* xi_g = xb + (size_t)li0 * XS;
    float ni[8];
    #pragma unroll
    for (int t = 0; t < 8; ++t) ni[t] = nrm[b * NN + li0 + t];
    #pragma unroll 1
    for (int s = 0; s < 2; ++s) {
        const int j0 = tid + 1024 * s;           // rows j0 + 256*q, q=0..3
        float nj[4];
        #pragma unroll
        for (int q = 0; q < 4; ++q) nj[q] = nrm[b * NN + j0 + 256 * q];
        float acc[8][4];
        #pragma unroll
        for (int t = 0; t < 8; ++t)
            #pragma unroll
            for (int q = 0; q < 4; ++q) acc[t][q] = 0.f;
        #pragma unroll 1
        for (int c = 0; c < C; c += 16) {
            float4 v[4][4];
            #pragma unroll
            for (int q = 0; q < 4; ++q) {
                const float* xj = xb + (size_t)(j0 + 256 * q) * XS + c;
                v[q][0] = *(const float4*)(xj);
                v[q][1] = *(const float4*)(xj + 4);
                v[q][2] = *(const float4*)(xj + 8);
                v[q][3] = *(const float4*)(xj + 12);
            }
            #pragma unroll
            for (int t = 0; t < 8; ++t) {
                const float* xr = xi_g + (size_t)t * XS + c;   // wave-uniform
                float4 a0 = *(const float4*)(xr);
                float4 a1 = *(const float4*)(xr + 4);
                float4 a2 = *(const float4*)(xr + 8);
                float4 a3 = *(const float4*)(xr + 12);
                #pragma unroll
                for (int q = 0; q < 4; ++q) {
                    float sum = acc[t][q];
                    sum += a0.x * v[q][0].x; sum += a0.y * v[q][0].y;
                    sum += a0.z * v[q][0].z; sum += a0.w * v[q][0].w;
                    sum += a1.x * v[q][1].x; sum += a1.y * v[q][1].y;
                    sum += a1.z * v[q][1].z; sum += a1.w * v[q][1].w;
                    sum += a2.x * v[q][2].x; sum += a2.y * v[q][2].y;
                    sum += a2.z * v[q][2].z; sum += a2.w * v[q][2].w;
                    sum += a3.x * v[q][3].x; sum += a3.y * v[q][3].y;
                    sum += a3.z * v[q][3].z; sum += a3.w * v[q][3].w;
                    acc[t][q] = sum;
                }
            }
        }
        #pragma unroll
        for (int t = 0; t < 8; ++t)
            #pragma unroll
            for (int q = 0; q < 4; ++q)
                dist[t][j0 + 256 * q] = 2.f * acc[t][q] - ni[t] - nj[q];
    }
    __syncthreads();
    const int w = tid >> 6;
    const int lane = tid & 63;
    #pragma unroll 1
    for (int rr = 0; rr < 2; ++rr) {
        const int t = w + 4 * rr;
        float lv[32];
        #pragma unroll
        for (int m = 0; m < 32; ++m) lv[m] = dist[t][m * 64 + lane];
        wave_topk<20>(lv, lane, idx20 + (size_t)(i0 + t) * 20);
    }
}

// ---------------------------------------------------------------------------
// Kernel 4T v7 (FINAL): 8 rows, 512 thr, single-pass xT, XCD swizzle.
// R12: swizzle made xT L2-served (FETCH 74->16.5 MB); VALUBusy 84% at
// 2 blocks/CU. R13's 4-block two-phase variant regressed (occ 37%, extra
// barriers + half-idle extraction waves) -> this v7 shape is the verified
// local optimum: VALU-issue-bound, memory minimized, bit-identical dist
// (c-ascending FMA order) -> identical topk indices.
// ---------------------------------------------------------------------------
template<int C>
__global__ __launch_bounds__(512, 4) void topk_feat_t(
        const float* __restrict__ xin, const float* __restrict__ xT,
        const float* __restrict__ nrm, int* __restrict__ idx20) {
    const int nwg = gridDim.x;                   // BN/8 = 4096 (div by 8)
    const int bid = blockIdx.x;
    const int swz = (bid & 7) * (nwg >> 3) + (bid >> 3);
    const int i0 = swz * 8;                      // global point index
    const int b = i0 >> 11;
    const int li0 = i0 & (NN - 1);
    __shared__ float dist[8][NN];                // 64 KB
    __shared__ float xi[8][C];                   // <= 4 KB
    const int tid = threadIdx.x;                 // 0..511
    for (int t4 = tid * 4; t4 < 8 * C; t4 += 2048) {
        const int t = t4 / C, c = t4 % C;
        *(float4*)&xi[t][c] = *(const float4*)&xin[(size_t)(i0 + t) * XS + c];
    }
    float ni[8];
    #pragma unroll
    for (int t = 0; t < 8; ++t) ni[t] = nrm[b * NN + li0 + t];
    const float4 nj = *(const float4*)&nrm[b * NN + tid * 4];
    const float* xTb = xT + (size_t)b * C * NN;
    __syncthreads();
    float acc[8][4];
    #pragma unroll
    for (int t = 0; t < 8; ++t)
        #pragma unroll
        for (int j = 0; j < 4; ++j) acc[t][j] = 0.f;
    #pragma unroll 1
    for (int c0 = 0; c0 < C; c0 += 4) {
        float4 vj[4];
        #pragma unroll
        for (int cc = 0; cc < 4; ++cc)
            vj[cc] = *(const float4*)&xTb[(size_t)(c0 + cc) * NN + tid * 4];
        #pragma unroll
        for (int t = 0; t < 8; ++t) {
            const float4 av = *(const float4*)&xi[t][c0];
            // c-ascending per output element (bit-exact vs fused kernel)
            acc[t][0] += av.x * vj[0].x;
            acc[t][1] += av.x * vj[0].y;
            acc[t][2] += av.x * vj[0].z;
            acc[t][3] += av.x * vj[0].w;
            acc[t][0] += av.y * vj[1].x;
            acc[t][1] += av.y * vj[1].y;
            acc[t][2] += av.y * vj[1].z;
            acc[t][3] += av.y * vj[1].w;
            acc[t][0] += av.z * vj[2].x;
            acc[t][1] += av.z * vj[2].y;
            acc[t][2] += av.z * vj[2].z;
            acc[t][3] += av.z * vj[2].w;
            acc[t][0] += av.w * vj[3].x;
            acc[t][1] += av.w * vj[3].y;
            acc[t][2] += av.w * vj[3].z;
            acc[t][3] += av.w * vj[3].w;
        }
    }
    #pragma unroll
    for (int t = 0; t < 8; ++t) {
        float4 d;
        d.x = 2.f * acc[t][0] - ni[t] - nj.x;
        d.y = 2.f * acc[t][1] - ni[t] - nj.y;
        d.z = 2.f * acc[t][2] - ni[t] - nj.z;
        d.w = 2.f * acc[t][3] - ni[t] - nj.w;
        *(float4*)&dist[t][tid * 4] = d;
    }
    __syncthreads();
    const int w = tid >> 6;                      // 0..7: one wave per row
    const int lane = tid & 63;
    float lv[32];
    #pragma unroll
    for (int m = 0; m < 32; ++m) lv[m] = dist[w][m * 64 + lane];
    wave_topk<20>(lv, lane, idx20 + (size_t)(i0 + w) * 20);
}

// ---------------------------------------------------------------------------
// Kernel 5a: pconv — dense GEMM producing PT[BN][2*COUT]:
//   PT[i][o]      = sum_c w[o][c] * x[i][c]               (P)
//   PT[i][COUT+o] = sum_c (w[o][C+c]-w[o][c]) * x[i][c]   (T)
// R3: xt padded +4 floats/row (16-way LDS bank conflicts, 524K counted).
// ---------------------------------------------------------------------------
template<int C, int COUT>
__global__ __launch_bounds__(256) void pconv(
        const float* __restrict__ xin,   // rows stride XS
        const float* __restrict__ w,     // [COUT][2C]
        float* __restrict__ pt) {        // [BN][2*COUT] packed
    constexpr int O2 = 2 * COUT;
    constexpr int PB = 8192 / O2;
    constexpr int OG = O2 / 8;
    constexpr int PG = PB / 4;
    static_assert(OG * PG == 256, "tile mismatch");
    const int i0 = blockIdx.x * PB;
    __shared__ __align__(16) float xt[PB][C + 4];
    const int tid = threadIdx.x;
    for (int t = tid * 4; t < PB * C; t += 1024)
        *(float4*)(&xt[t / C][t % C]) =
            *(const float4*)(&xin[(size_t)(i0 + t / C) * XS + (t % C)]);
    __syncthreads();
    const int og = tid % OG, pg = tid / OG;
    const int o0 = og * 8, p0 = pg * 4;
    const bool thalf = (o0 >= COUT);
    const float* wb0 = w + (size_t)(thalf ? o0 - COUT : o0) * 2 * C;
    float acc[8][4];
    #pragma unroll
    for (int r = 0; r < 8; ++r)
        #pragma unroll
        for (int p = 0; p < 4; ++p) acc[r][p] = 0.f;
    #pragma unroll 2
    for (int c = 0; c < C; c += 4) {
        float4 wf[8];
        if (thalf) {
            #pragma unroll
            for (int r = 0; r < 8; ++r) {
                float4 a = *(const float4*)(wb0 + (size_t)r * 2 * C + c);
                float4 bq = *(const float4*)(wb0 + (size_t)r * 2 * C + C + c);
                wf[r].x = bq.x - a.x; wf[r].y = bq.y - a.y;
                wf[r].z = bq.z - a.z; wf[r].w = bq.w - a.w;
            }
        } else {
            #pragma unroll
            for (int r = 0; r < 8; ++r)
                wf[r] = *(const float4*)(wb0 + (size_t)r * 2 * C + c);
        }
        #pragma unroll
        for (int p = 0; p < 4; ++p) {
            float4 xv = *(const float4*)(&xt[p0 + p][c]);
            #pragma unroll
            for (int r = 0; r < 8; ++r)
                acc[r][p] += wf[r].x * xv.x + wf[r].y * xv.y
                           + wf[r].z * xv.z + wf[r].w * xv.w;
        }
    }
    #pragma unroll
    for (int p = 0; p < 4; ++p) {
        float* dst = pt + (size_t)(i0 + p0 + p) * O2 + o0;
        *(float4*)(dst)     = make_float4(acc[0][p], acc[1][p], acc[2][p], acc[3][p]);
        *(float4*)(dst + 4) = make_float4(acc[4][p], acc[5][p], acc[6][p], acc[7][p]);
    }
}

// ---------------------------------------------------------------------------
// Kernel 5b: gmax — gather 20 neighbor P-rows, max/min, select by sign(s),
// add T, bn+leaky, store into xcat (stride XS). idx20 is batch-local.
// ---------------------------------------------------------------------------
template<int COUT>
__global__ __launch_bounds__(256) void gmax(
        const float* __restrict__ pt, const int* __restrict__ idx20,
        const float* __restrict__ g, const float* __restrict__ bb,
        float* __restrict__ xout) {
    constexpr int TPP = COUT / 4;
    constexpr int PTS = 256 / TPP;
    const int i0 = blockIdx.x * PTS;
    const int base = i0 & ~(NN - 1);
    __shared__ int jl[PTS][20];
    const int tid = threadIdx.x;
    for (int t = tid; t < PTS * 20; t += 256)
        jl[t / 20][t % 20] = idx20[(size_t)(i0 + t / 20) * 20 + (t % 20)];
    __syncthreads();
    const int p = tid / TPP;
    const int q = (tid % TPP) * 4;
    const int i = i0 + p;
    float4 mx = make_float4(-INFINITY, -INFINITY, -INFINITY, -INFINITY);
    float4 mn = make_float4(INFINITY, INFINITY, INFINITY, INFINITY);
    #pragma unroll 4
    for (int k = 0; k < 20; ++k) {
        float4 v = *(const float4*)(pt + (size_t)(base + jl[p][k]) * (2 * COUT) + q);
        mx.x = fmaxf(mx.x, v.x); mx.y = fmaxf(mx.y, v.y);
        mx.z = fmaxf(mx.z, v.z); mx.w = fmaxf(mx.w, v.w);
        mn.x = fminf(mn.x, v.x); mn.y = fminf(mn.y, v.y);
        mn.z = fminf(mn.z, v.z); mn.w = fminf(mn.w, v.w);
    }
    float4 tv = *(const float4*)(pt + (size_t)i * (2 * COUT) + COUT + q);
    float4 gv = *(const float4*)(g + q);
    float4 bv = *(const float4*)(bb + q);
    float4 res;
    {
        float s = bnscale(gv.x); res.x = leaky(((s >= 0.f ? mx.x : mn.x) + tv.x) * s + bv.x);
    }{
        float s = bnscale(gv.y); res.y = leaky(((s >= 0.f ? mx.y : mn.y) + tv.y) * s + bv.y);
    }{
        float s = bnscale(gv.z); res.z = leaky(((s >= 0.f ? mx.z : mn.z) + tv.z) * s + bv.z);
    }{
        float s = bnscale(gv.w); res.w = leaky(((s >= 0.f ? mx.w : mn.w) + tv.w) * s + bv.w);
    }
    *(float4*)(xout + (size_t)i * XS + q) = res;
}

// ---------------------------------------------------------------------------
// Kernel S: split fp32 -> bf16 hi/lo pair (round-to-nearest-even).
// v = hi + lo + O(2^-18 |v|).
// ---------------------------------------------------------------------------
__global__ __launch_bounds__(256) void split_bf16(const float* __restrict__ in,
                                                  u16* __restrict__ hi,
                                                  u16* __restrict__ lo, int n4) {
    int i = blockIdx.x * 256 + threadIdx.x;
    if (i >= n4) return;
    float4 v = ((const float4*)in)[i];
    float vv[4] = {v.x, v.y, v.z, v.w};
    unsigned h[4], l[4];
    #pragma unroll
    for (int t = 0; t < 4; ++t) {
        unsigned u = __float_as_uint(vv[t]);
        unsigned r = (u + 0x7FFFu + ((u >> 16) & 1u)) >> 16;
        h[t] = r;
        float res = vv[t] - __uint_as_float(r << 16);
        unsigned u2 = __float_as_uint(res);
        l[t] = (u2 + 0x7FFFu + ((u2 >> 16) & 1u)) >> 16;
    }
    ((uint2*)hi)[i] = make_uint2(h[0] | (h[1] << 16), h[2] | (h[3] << 16));
    ((uint2*)lo)[i] = make_uint2(l[0] | (l[1] << 16), l[2] | (l[3] << 16));
}

// ---------------------------------------------------------------------------
// Kernel 6 (MFMA, v2): w5 conv via bf16x3 split-float MFMA, register-tiled.
// Each wave owns a 64x64 tile (4 m-frags x 4 n-frags, 64 acc VGPRs);
// block = 4 waves = 64 m x 256 oc. R2: dropped 576 -> <100 µs vs v1.
// ---------------------------------------------------------------------------
__global__ __launch_bounds__(256) void conv5_mfma2(
        const u16* __restrict__ xhi, const u16* __restrict__ xlo,
        const u16* __restrict__ whi, const u16* __restrict__ wlo,
        const float* __restrict__ g5, const float* __restrict__ b5,
        float* __restrict__ pmax, float* __restrict__ psum) {
    const int mblk = blockIdx.x >> 2;            // BN/64 m-blocks
    const int nblk = blockIdx.x & 3;             // 4 n-groups x 256 oc
    const int wv = threadIdx.x >> 6;
    const int lane = threadIdx.x & 63;
    const int row = lane & 15;
    const int quad = lane >> 4;
    const int m0 = mblk * 64;
    const int n0 = nblk * 256 + wv * 64;
    const u16* xh = xhi + (size_t)(m0 + row) * 512 + quad * 8;
    const u16* xl = xlo + (size_t)(m0 + row) * 512 + quad * 8;
    const u16* wh = whi + (size_t)(n0 + row) * 512 + quad * 8;
    const u16* wl = wlo + (size_t)(n0 + row) * 512 + quad * 8;
    f32x4 acc[4][4];
    #pragma unroll
    for (int f = 0; f < 4; ++f)
        #pragma unroll
        for (int g = 0; g < 4; ++g) acc[f][g] = (f32x4){0.f, 0.f, 0.f, 0.f};
    #pragma unroll 1
    for (int k = 0; k < 512; k += 32) {
        short8 ah[4], al[4], bh[4], bl[4];
        #pragma unroll
        for (int f = 0; f < 4; ++f) {
            ah[f] = *(const short8*)(xh + (size_t)f * 16 * 512 + k);
            al[f] = *(const short8*)(xl + (size_t)f * 16 * 512 + k);
        }
        #pragma unroll
        for (int g = 0; g < 4; ++g) {
            bh[g] = *(const short8*)(wh + (size_t)g * 16 * 512 + k);
            bl[g] = *(const short8*)(wl + (size_t)g * 16 * 512 + k);
        }
        #pragma unroll
        for (int f = 0; f < 4; ++f)
            #pragma unroll
            for (int g = 0; g < 4; ++g) {
                acc[f][g] = __builtin_amdgcn_mfma_f32_16x16x32_bf16(ah[f], bh[g], acc[f][g], 0, 0, 0);
                acc[f][g] = __builtin_amdgcn_mfma_f32_16x16x32_bf16(ah[f], bl[g], acc[f][g], 0, 0, 0);
                acc[f][g] = __builtin_amdgcn_mfma_f32_16x16x32_bf16(al[f], bh[g], acc[f][g], 0, 0, 0);
            }
    }
    const int b = m0 >> 11;
    const int ch0 = (m0 & (NN - 1)) >> 4;        // chunk of 16 pts
    #pragma unroll
    for (int f = 0; f < 4; ++f) {
        const int ch = ch0 + f;
        #pragma unroll
        for (int g = 0; g < 4; ++g) {
            const int oc = n0 + g * 16 + row;
            float s = bnscale(g5[oc]), bv = b5[oc];
            float mx = -INFINITY, sm = 0.f;
            #pragma unroll
            for (int r = 0; r < 4; ++r) {
                float z = leaky(acc[f][g][r] * s + bv);
                mx = fmaxf(mx, z); sm += z;
            }
            mx = fmaxf(mx, __shfl_xor(mx, 16)); sm += __shfl_xor(sm, 16);
            mx = fmaxf(mx, __shfl_xor(mx, 32)); sm += __shfl_xor(sm, 32);
            if (lane < 16) {
                pmax[((size_t)b * 128 + ch) * 1024 + oc] = mx;
                psum[((size_t)b * 128 + ch) * 1024 + oc] = sm;
            }
        }
    }
}

// ---------------------------------------------------------------------------
// Kernel 6 (fallback): fp32 conv5+pool, 32 pts/block, 64 chunks.
// ---------------------------------------------------------------------------
__global__ __launch_bounds__(256, 3) void conv5_pool(
        const float* __restrict__ xcat,
        const float* __restrict__ w5, const float* __restrict__ g5,
        const float* __restrict__ b5,
        float* __restrict__ pmax, float* __restrict__ psum) {
    const int blk = blockIdx.x;                  // b*64 + chunk
    const int b = blk >> 6;
    const int ch = blk & 63;
    const int i0 = ch * 32;
    const float* xrow = xcat + ((size_t)b * NN + i0) * XS;
    const int tid = threadIdx.x;
    float acc[4][32];
    #pragma unroll
    for (int q = 0; q < 4; ++q)
        #pragma unroll
        for (int p = 0; p < 32; ++p) acc[q][p] = 0.f;
    #pragma unroll 1
    for (int c = 0; c < 512; c += 4) {
        float4 wv[4];
        #pragma unroll
        for (int q = 0; q < 4; ++q)
            wv[q] = *(const float4*)(w5 + (size_t)(tid + 256 * q) * 512 + c);
        #pragma unroll
        for (int p = 0; p < 32; ++p) {
            float4 xs = *(const float4*)(xrow + (size_t)p * XS + c);
            #pragma unroll
            for (int q = 0; q < 4; ++q)
                acc[q][p] += wv[q].x * xs.x + wv[q].y * xs.y
                           + wv[q].z * xs.z + wv[q].w * xs.w;
        }
    }
    #pragma unroll
    for (int q = 0; q < 4; ++q) {
        int oc = tid + 256 * q;
        float s = bnscale(g5[oc]), bv = b5[oc];
        float m = -INFINITY, sm = 0.f;
        #pragma unroll
        for (int p = 0; p < 32; ++p) {
            float z = leaky(acc[q][p] * s + bv);
            m = fmaxf(m, z);
            sm += z;
        }
        pmax[((size_t)b * 64 + ch) * 1024 + oc] = m;
        psum[((size_t)b * 64 + ch) * 1024 + oc] = sm;
    }
}

// ---------------------------------------------------------------------------
// Kernel 6b: pool_reduce — reduce pmax/psum over nch chunks into h[b][2048]
// with real parallelism (BB*8 = 128 blocks, coalesced 1024-wide reads).
// ---------------------------------------------------------------------------
__global__ __launch_bounds__(256) void pool_reduce(
        const float* __restrict__ pmax, const float* __restrict__ psum,
        int nch, float* __restrict__ hbuf) {
    const int b = blockIdx.x >> 3;
    const int g = blockIdx.x & 7;                // 8 oc-groups of 128
    const int tid = threadIdx.x;
    const int oc = g * 128 + (tid & 127);
    const int half = tid >> 7;                   // 2 chunk-halves
    const int h0 = half * (nch / 2);
    float m = -INFINITY, sm = 0.f;
    for (int ch = h0; ch < h0 + nch / 2; ++ch) {
        m = fmaxf(m, pmax[((size_t)b * nch + ch) * 1024 + oc]);
        sm += psum[((size_t)b * nch + ch) * 1024 + oc];
    }
    __shared__ float sx[128], ss[128];
    if (half == 1) { sx[tid & 127] = m; ss[tid & 127] = sm; }
    __syncthreads();
    if (half == 0) {
        m = fmaxf(m, sx[tid & 127]);
        sm += ss[tid & 127];
        hbuf[(size_t)b * 2048 + oc] = m;
        hbuf[(size_t)b * 2048 + 1024 + oc] = sm * (1.0f / 2048.0f);
    }
}

// ---------------------------------------------------------------------------
// Kernel 7: 3 FC layers on precomputed h. One block per batch row.
// ---------------------------------------------------------------------------
__global__ __launch_bounds__(256) void fc_head(
        const float* __restrict__ hbuf,
        const float* __restrict__ wl1, const float* __restrict__ g6, const float* __restrict__ b6,
        const float* __restrict__ wl2, const float* __restrict__ bl2,
        const float* __restrict__ g7, const float* __restrict__ b7,
        const float* __restrict__ wl3, const float* __restrict__ bl3,
        float* __restrict__ out) {
    const int b = blockIdx.x;
    const int tid = threadIdx.x;
    __shared__ float h[2048];
    __shared__ float h1[512];
    __shared__ float h2[256];
    for (int t = tid * 4; t < 2048; t += 1024)
        *(float4*)(&h[t]) = *(const float4*)(hbuf + (size_t)b * 2048 + t);
    __syncthreads();
    #pragma unroll
    for (int q = 0; q < 2; ++q) {
        int o = tid + 256 * q;
        const float* wr = wl1 + (size_t)o * 2048;
        float y = 0.f;
        for (int c = 0; c < 2048; c += 4) {
            float4 wv = *(const float4*)(wr + c);
            float4 hv = *(const float4*)(&h[c]);
            y += wv.x * hv.x + wv.y * hv.y + wv.z * hv.z + wv.w * hv.w;
        }
        y = y * bnscale(g6[o]) + b6[o];
        h1[o] = leaky(y);
    }
    __syncthreads();
    {
        int o = tid;
        const float* wr = wl2 + (size_t)o * 512;
        float y = 0.f;
        for (int c = 0; c < 512; c += 4) {
            float4 wv = *(const float4*)(wr + c);
            float4 hv = *(const float4*)(&h1[c]);
            y += wv.x * hv.x + wv.y * hv.y + wv.z * hv.z + wv.w * hv.w;
        }
        y = (y + bl2[o]) * bnscale(g7[o]) + b7[o];
        h2[o] = leaky(y);
    }
    __syncthreads();
    if (tid < 7) {
        const float* wr = wl3 + tid * 256;
        float y = 0.f;
        for (int c = 0; c < 256; ++c) y += wr[c] * h2[c];
        out[b * 7 + tid] = y + bl3[tid];
    }
}

// ---------------------------------------------------------------------------
extern "C" void kernel_launch(void* const* d_in, const int* in_sizes, int n_in,
                              void* d_out, int out_size, void* d_ws, size_t ws_size,
                              hipStream_t stream) {
    const float* x   = (const float*)d_in[0];
    const float* w1l = (const float*)d_in[1];
    const float* g1l = (const float*)d_in[2];
    const float* b1l = (const float*)d_in[3];
    const float* w1b = (const float*)d_in[4];
    const float* g1b = (const float*)d_in[5];
    const float* b1b = (const float*)d_in[6];
    const float* w1c = (const float*)d_in[7];
    const float* g1c = (const float*)d_in[8];
    const float* b1c = (const float*)d_in[9];
    const float* wf  = (const float*)d_in[10];
    const float* gf  = (const float*)d_in[11];
    const float* bf_ = (const float*)d_in[12];
    const float* w2  = (const float*)d_in[13];
    const float* g2  = (const float*)d_in[14];
    const float* b2  = (const float*)d_in[15];
    const float* w3  = (const float*)d_in[16];
    const float* g3  = (const float*)d_in[17];
    const float* b3  = (const float*)d_in[18];
    const float* w4  = (const float*)d_in[19];
    const float* g4  = (const float*)d_in[20];
    const float* b4  = (const float*)d_in[21];
    const float* w5  = (const float*)d_in[22];
    const float* g5  = (const float*)d_in[23];
    const float* b5  = (const float*)d_in[24];
    const float* wl1 = (const float*)d_in[25];
    const float* g6  = (const float*)d_in[26];
    const float* b6  = (const float*)d_in[27];
    const float* wl2 = (const float*)d_in[28];
    const float* bl2 = (const float*)d_in[29];
    const float* g7  = (const float*)d_in[30];
    const float* b7  = (const float*)d_in[31];
    const float* wl3 = (const float*)d_in[32];
    const float* bl3 = (const float*)d_in[33];
    float* out = (float*)d_out;

    // Workspace layout (MB offsets):
    //  idxb [0,4)  xcat [4,68)  nrm [68,68.125)  hbuf [68.25,68.5)  pt [69,101)
    //  xT [69,85): transposed features, live ONLY between transpose_feat and
    //    topk_feat_t of each stage — pt/xlo (dead then) overlay it afterward.
    //  MFMA path (needs 151 MB): xlo overlays pt [69,101), xhi [101,133),
    //  whi [133,134), wlo [134,135), pmax [135,143), psum [143,151)
    //  Fallback (<151 MB): pmax [69,73), psum [73,77) (64-chunk), fused topk.
    char* ws = (char*)d_ws;
    int*   idxb = (int*)(ws);
    float* xcat = (float*)(ws + ((size_t)4  << 20));
    float* nrm  = (float*)(ws + ((size_t)68 << 20));
    float* hbuf = (float*)(ws + ((size_t)68 << 20) + ((size_t)256 << 10));
    float* pt   = (float*)(ws + ((size_t)69 << 20));
    float* xT   = (float*)(ws + ((size_t)69 << 20));
    const bool mfma_ok = ws_size >= ((size_t)151 << 20);
    u16* xlo = (u16*)(ws + ((size_t)69  << 20));
    u16* xhi = (u16*)(ws + ((size_t)101 << 20));
    u16* whi = (u16*)(ws + ((size_t)133 << 20));
    u16* wlo = (u16*)(ws + ((size_t)134 << 20));
    float* pmax = mfma_ok ? (float*)(ws + ((size_t)135 << 20))
                          : (float*)(ws + ((size_t)69 << 20));
    float* psum = mfma_ok ? (float*)(ws + ((size_t)143 << 20))
                          : (float*)(ws + ((size_t)73 << 20));
    const int nch = mfma_ok ? 128 : 64;
    float* x1 = xcat;
    float* x2 = xcat + 64;
    float* x3 = xcat + 128;
    float* x4 = xcat + 256;

    // 1. top-30 on xyz
    topk_xyz<<<BB * NN / 4, 256, 0, stream>>>(x, idxb);
    // 2. hierarchical scale convs + wf conv -> x1 slice of xcat
    hier_conv<<<BB * NN, 64, 0, stream>>>(x, idxb, w1l, g1l, b1l, w1b, g1b, b1b,
                                          w1c, g1c, b1c, wf, gf, bf_, x1);
    // 3. edge stage 2: x1(64) -> x2(64)
    rownorm<64><<<BN / 256, 256, 0, stream>>>(x1, nrm);
    if (mfma_ok) {
        transpose_feat<64><<<BB * 32, 256, 0, stream>>>(x1, xT);
        topk_feat_t<64><<<BN / 8, 512, 0, stream>>>(x1, xT, nrm, idxb);
    } else {
        topk_feat<64><<<BN / 8, 256, 0, stream>>>(x1, nrm, idxb);
    }
    pconv<64, 64><<<BN / 64, 256, 0, stream>>>(x1, w2, pt);
    gmax<64><<<BN / 16, 256, 0, stream>>>(pt, idxb, g2, b2, x2);
    // 4. edge stage 3: x2(64) -> x3(128)
    rownorm<64><<<BN / 256, 256, 0, stream>>>(x2, nrm);
    if (mfma_ok) {
        transpose_feat<64><<<BB * 32, 256, 0, stream>>>(x2, xT);
        topk_feat_t<64><<<BN / 8, 512, 0, stream>>>(x2, xT, nrm, idxb);
    } else {
        topk_feat<64><<<BN / 8, 256, 0, stream>>>(x2, nrm, idxb);
    }
    pconv<64, 128><<<BN / 32, 256, 0, stream>>>(x2, w3, pt);
    gmax<128><<<BN / 8, 256, 0, stream>>>(pt, idxb, g3, b3, x3);
    // 5. edge stage 4: x3(128) -> x4(256), two column halves
    rownorm<128><<<BN / 256, 256, 0, stream>>>(x3, nrm);
    if (mfma_ok) {
        transpose_feat<128><<<BB * 32, 256, 0, stream>>>(x3, xT);
        topk_feat_t<128><<<BN / 8, 512, 0, stream>>>(x3, xT, nrm, idxb);
    } else {
        topk_feat<128><<<BN / 8, 256, 0, stream>>>(x3, nrm, idxb);
    }
    for (int h = 0; h < 2; ++h) {
        pconv<128, 128><<<BN / 32, 256, 0, stream>>>(x3, w4 + (size_t)h * 128 * 256, pt);
        gmax<128><<<BN / 8, 256, 0, stream>>>(pt, idxb, g4 + h * 128, b4 + h * 128,
                                              x4 + h * 128);
    }
    // 6. w5 conv + pooling partials
    if (mfma_ok) {
        split_bf16<<<(BN * 512 / 4) / 256, 256, 0, stream>>>(xcat, xhi, xlo, BN * 512 / 4);
        split_bf16<<<(1024 * 512 / 4) / 256, 256, 0, stream>>>(w5, whi, wlo, 1024 * 512 / 4);
        conv5_mfma2<<<(BN / 64) * 4, 256, 0, stream>>>(xhi, xlo, whi, wlo,
                                                       g5, b5, pmax, psum);
    } else {
        conv5_pool<<<BB * 64, 256, 0, stream>>>(xcat, w5, g5, b5, pmax, psum);
    }
    // 7. parallel pool reduce + FC head
    pool_reduce<<<BB * 8, 256, 0, stream>>>(pmax, psum, nch, hbuf);
    fc_head<<<BB, 256, 0, stream>>>(hbuf, wl1, g6, b6, wl2, bl2,
                                    g7, b7, wl3, bl3, out);
}